// Round 6
// baseline (48.388 us; speedup 1.0000x reference)
//
#include <hip/hip_runtime.h>

#define Bn 4
#define Sn 512
#define Hn 128
#define ST 4   // s-rows per score/softpv block

__device__ __forceinline__ float fast_exp2(float x) { return __builtin_amdgcn_exp2f(x); }
__device__ __forceinline__ float fast_rcp(float x)  { return __builtin_amdgcn_rcpf(x); }

#define C2 2.8853900817779268f   // 2*log2(e)

// Kernel 1: eq[b][s][h] = exp2(C2*(q@Wq^T + bias)) ; ekT[b][h][t] = exp2(C2*(k@Wk^T))
// 4 rows per block, 512 blocks (2 blocks/CU).
__global__ __launch_bounds__(256) void proj_kernel(
    const float* __restrict__ query, const float* __restrict__ key,
    const float* __restrict__ attn_W, const float* __restrict__ attn_b,
    float* __restrict__ eq, float* __restrict__ ekT)
{
    __shared__ float rows[2][4][Hn];       // 4 KB
    const int row0 = blockIdx.x * 4;       // global (b*S+s) row
    const int b    = row0 / Sn;
    const int t0   = row0 % Sn;            // multiple of 4
    const int tid  = threadIdx.x;

    {   // 2*4*128 floats = 256 float4, one per thread
        int src = tid >> 7, r = (tid >> 5) & 3, c4 = tid & 31;
        ((float4*)rows)[tid] =
            reinterpret_cast<const float4*>(src ? key : query)[(row0 + r) * 32 + c4];
    }
    __syncthreads();

    const int o     = tid & 127;
    const int which = tid >> 7;            // 0 = q-proj, 1 = k-proj (wave-uniform)
    float acc[4] = {0,0,0,0};
    const float* wrow = attn_W + o * (2 * Hn) + which * Hn;
    for (int c = 0; c < Hn; c += 4) {
        float4 wv = *reinterpret_cast<const float4*>(wrow + c);
        #pragma unroll
        for (int r = 0; r < 4; r++) {
            float4 rv = *reinterpret_cast<const float4*>(&rows[which][r][c]); // b128 broadcast
            acc[r] += rv.x * wv.x + rv.y * wv.y + rv.z * wv.z + rv.w * wv.w;
        }
    }
    if (which == 0) {
        float bias = attn_b[o];
        #pragma unroll
        for (int r = 0; r < 4; r++)
            eq[(row0 + r) * Hn + o] = fast_exp2(C2 * (acc[r] + bias));
    } else {
        float4 ev;
        ev.x = fast_exp2(C2 * acc[0]); ev.y = fast_exp2(C2 * acc[1]);
        ev.z = fast_exp2(C2 * acc[2]); ev.w = fast_exp2(C2 * acc[3]);
        *reinterpret_cast<float4*>(&ekT[(size_t)(b * Hn + o) * Sn + t0]) = ev;
    }
}

// Kernel 2: partial logits, LDS-free, sync-free.
// grid (Sn/ST=128, Bn, 2 t-halves) = 1024 blocks x 256 threads.
// thread = (h-half hh, s in 4, tc in 32): 8 t columns x 64 h, all in registers.
// pl[hh][b][s][t] = -2 * sum_{h in half} v_w[h] * rcp(eq*ek + 1)
__global__ __launch_bounds__(256) void score_kernel(
    const float* __restrict__ eq, const float* __restrict__ ekT,
    const float* __restrict__ v_w, float* __restrict__ pl)
{
    const int b    = blockIdx.y;
    const int s0   = blockIdx.x * ST;
    const int tid  = threadIdx.x;
    const int hh   = tid >> 7;           // h-half (wave-uniform)
    const int loc  = tid & 127;
    const int s    = loc >> 5;           // 0..3
    const int tc   = loc & 31;           // 0..31
    const int t0g  = blockIdx.z * 256 + tc * 8;

    const float* kb   = ekT + ((size_t)b * Hn + hh * 64) * Sn + t0g;
    const float* qrow = eq + (size_t)(b * Sn + s0 + s) * Hn + hh * 64;
    const float* wrow = v_w + hh * 64;

    float acc[8] = {0,0,0,0,0,0,0,0};
    float4 e0[4], e1[4];
    #pragma unroll
    for (int j = 0; j < 4; j++) {
        e0[j] = *reinterpret_cast<const float4*>(kb + (size_t)j * Sn);
        e1[j] = *reinterpret_cast<const float4*>(kb + (size_t)j * Sn + 4);
    }
    float4 q4 = *reinterpret_cast<const float4*>(qrow);
    float4 w4 = *reinterpret_cast<const float4*>(wrow);

    for (int g = 0; g < 64; g += 4) {
        float4 n0[4], n1[4], nq4, nw4;
        const bool more = (g + 4 < 64);
        if (more) {
            const float* kn = kb + (size_t)(g + 4) * Sn;
            #pragma unroll
            for (int j = 0; j < 4; j++) {
                n0[j] = *reinterpret_cast<const float4*>(kn + (size_t)j * Sn);
                n1[j] = *reinterpret_cast<const float4*>(kn + (size_t)j * Sn + 4);
            }
            nq4 = *reinterpret_cast<const float4*>(qrow + g + 4);
            nw4 = *reinterpret_cast<const float4*>(wrow + g + 4);
        }
        const float qj[4] = {q4.x, q4.y, q4.z, q4.w};
        const float wj[4] = {w4.x, w4.y, w4.z, w4.w};
        #pragma unroll
        for (int j = 0; j < 4; j++) {
            const float q = qj[j], w = wj[j];
            acc[0] += w * fast_rcp(q * e0[j].x + 1.0f);
            acc[1] += w * fast_rcp(q * e0[j].y + 1.0f);
            acc[2] += w * fast_rcp(q * e0[j].z + 1.0f);
            acc[3] += w * fast_rcp(q * e0[j].w + 1.0f);
            acc[4] += w * fast_rcp(q * e1[j].x + 1.0f);
            acc[5] += w * fast_rcp(q * e1[j].y + 1.0f);
            acc[6] += w * fast_rcp(q * e1[j].z + 1.0f);
            acc[7] += w * fast_rcp(q * e1[j].w + 1.0f);
        }
        if (more) {
            #pragma unroll
            for (int j = 0; j < 4; j++) { e0[j] = n0[j]; e1[j] = n1[j]; }
            q4 = nq4; w4 = nw4;
        }
    }

    float4 o0, o1;
    o0.x = -2.0f * acc[0]; o0.y = -2.0f * acc[1];
    o0.z = -2.0f * acc[2]; o0.w = -2.0f * acc[3];
    o1.x = -2.0f * acc[4]; o1.y = -2.0f * acc[5];
    o1.z = -2.0f * acc[6]; o1.w = -2.0f * acc[7];
    float* dst = pl + (((size_t)hh * Bn + b) * Sn + (s0 + s)) * Sn + t0g;
    *reinterpret_cast<float4*>(dst)     = o0;
    *reinterpret_cast<float4*>(dst + 4) = o1;
}

// Kernel 3: softmax (summing the 2 h-half strips) + PV.  512 threads, grid (Sn/ST, Bn).
__global__ __launch_bounds__(512) void softpv_kernel(
    const float* __restrict__ value, const float* __restrict__ pl,
    float* __restrict__ out, float* __restrict__ out_w)
{
    __shared__ float4 scT4[Sn];               // weights transposed  8 KB
    __shared__ float4 part4[16][ST][Hn / 4];  // PV partials        32 KB

    const int b   = blockIdx.y;
    const int s0  = blockIdx.x * ST;
    const int tid = threadIdx.x;
    const int wave = tid >> 6, lane = tid & 63;

    if (wave < ST) {
        const int sr = wave;
        const float* r0 = pl + ((size_t)(0 * Bn + b) * Sn + (s0 + sr)) * Sn;
        const float* r1 = pl + ((size_t)(1 * Bn + b) * Sn + (s0 + sr)) * Sn;
        float v[8]; float m = -1e30f;
        #pragma unroll
        for (int i = 0; i < 8; i++) {
            v[i] = r0[lane + i * 64] + r1[lane + i * 64];
            m = fmaxf(m, v[i]);
        }
        #pragma unroll
        for (int off = 32; off; off >>= 1) m = fmaxf(m, __shfl_xor(m, off, 64));
        float sum = 0.f;
        const float l2e = 1.4426950408889634f;
        #pragma unroll
        for (int i = 0; i < 8; i++) { v[i] = fast_exp2((v[i] - m) * l2e); sum += v[i]; }
        #pragma unroll
        for (int off = 32; off; off >>= 1) sum += __shfl_xor(sum, off, 64);
        float inv = 1.0f / sum;
        float* wrow_out = out_w + (size_t)(b * Sn + s0 + sr) * Sn;
        #pragma unroll
        for (int i = 0; i < 8; i++) {
            float wgt = v[i] * inv;
            wrow_out[lane + i * 64] = wgt;             // normalized weights out
            ((float*)&scT4[lane + i * 64])[sr] = wgt;  // transposed copy for PV
        }
    }
    __syncthreads();

    // PV: thread = (tg in 16, hq in 32); value read once per block
    {
        const int hq = tid & 31, tg = tid >> 5;
        const float* vb = value + ((size_t)b * Sn + tg * 32) * Hn + hq * 4;
        float4 A0 = {0,0,0,0}, A1 = {0,0,0,0}, A2 = {0,0,0,0}, A3 = {0,0,0,0};
        #pragma unroll 4
        for (int i = 0; i < 32; i++) {
            float4 v4 = *reinterpret_cast<const float4*>(vb + i * Hn);
            float4 w4 = scT4[tg * 32 + i];     // b128 broadcast
            A0.x += w4.x * v4.x; A0.y += w4.x * v4.y; A0.z += w4.x * v4.z; A0.w += w4.x * v4.w;
            A1.x += w4.y * v4.x; A1.y += w4.y * v4.y; A1.z += w4.y * v4.z; A1.w += w4.y * v4.w;
            A2.x += w4.z * v4.x; A2.y += w4.z * v4.y; A2.z += w4.z * v4.z; A2.w += w4.z * v4.w;
            A3.x += w4.w * v4.x; A3.y += w4.w * v4.y; A3.z += w4.w * v4.z; A3.w += w4.w * v4.w;
        }
        part4[tg][0][hq] = A0;
        part4[tg][1][hq] = A1;
        part4[tg][2][hq] = A2;
        part4[tg][3][hq] = A3;
    }
    __syncthreads();
    {
        const int sg = tid >> 7, h = tid & 127;
        float r = 0.f;
        #pragma unroll
        for (int tg = 0; tg < 16; tg++)
            r += ((const float*)&part4[tg][sg][h >> 2])[h & 3];
        out[(b * Sn + s0 + sg) * Hn + h] = r;
    }
}

extern "C" void kernel_launch(void* const* d_in, const int* in_sizes, int n_in,
                              void* d_out, int out_size, void* d_ws, size_t ws_size,
                              hipStream_t stream) {
    const float* query  = (const float*)d_in[0];
    const float* key    = (const float*)d_in[1];
    const float* value  = (const float*)d_in[2];
    const float* attn_W = (const float*)d_in[3];
    const float* attn_b = (const float*)d_in[4];
    const float* v_w    = (const float*)d_in[5];

    float* out   = (float*)d_out;            // (B,S,H) then (B,S,S), both f32
    float* out_w = out + Bn * Sn * Hn;

    float* eq  = (float*)d_ws;               // B*S*H floats = 1 MB
    float* ekT = eq + Bn * Sn * Hn;          // B*H*S floats = 1 MB
    float* pl  = ekT + Bn * Hn * Sn;         // 2*B*S*S floats = 8 MB

    proj_kernel<<<Bn * Sn / 4, 256, 0, stream>>>(query, key, attn_W, attn_b, eq, ekT);
    score_kernel<<<dim3(Sn / ST, Bn, 2), 256, 0, stream>>>(eq, ekT, v_w, pl);
    softpv_kernel<<<dim3(Sn / ST, Bn), 512, 0, stream>>>(value, pl, out, out_w);
}

// Round 7
// 45.307 us; speedup vs baseline: 1.0680x; 1.0680x over previous
//
#include <hip/hip_runtime.h>

#define Bn 4
#define Sn 512
#define Hn 128
#define ST 4   // s-rows per score/softpv block

__device__ __forceinline__ float fast_exp2(float x) { return __builtin_amdgcn_exp2f(x); }
__device__ __forceinline__ float fast_rcp(float x)  { return __builtin_amdgcn_rcpf(x); }

#define C2 2.8853900817779268f   // 2*log2(e)

// Kernel 1: eq[b][s][h] = exp2(C2*(q@Wq^T + bias)) ; ekT[b][h][t] = exp2(C2*(k@Wk^T))
// 4 rows per block, 512 blocks (2 blocks/CU).
__global__ __launch_bounds__(256) void proj_kernel(
    const float* __restrict__ query, const float* __restrict__ key,
    const float* __restrict__ attn_W, const float* __restrict__ attn_b,
    float* __restrict__ eq, float* __restrict__ ekT)
{
    __shared__ float rows[2][4][Hn];       // 4 KB
    const int row0 = blockIdx.x * 4;       // global (b*S+s) row
    const int b    = row0 / Sn;
    const int t0   = row0 % Sn;            // multiple of 4
    const int tid  = threadIdx.x;

    {   // 2*4*128 floats = 256 float4, one per thread
        int src = tid >> 7, r = (tid >> 5) & 3, c4 = tid & 31;
        ((float4*)rows)[tid] =
            reinterpret_cast<const float4*>(src ? key : query)[(row0 + r) * 32 + c4];
    }
    __syncthreads();

    const int o     = tid & 127;
    const int which = tid >> 7;            // 0 = q-proj, 1 = k-proj (wave-uniform)
    float acc[4] = {0,0,0,0};
    const float* wrow = attn_W + o * (2 * Hn) + which * Hn;
    for (int c = 0; c < Hn; c += 4) {
        float4 wv = *reinterpret_cast<const float4*>(wrow + c);
        #pragma unroll
        for (int r = 0; r < 4; r++) {
            float4 rv = *reinterpret_cast<const float4*>(&rows[which][r][c]); // b128 broadcast
            acc[r] += rv.x * wv.x + rv.y * wv.y + rv.z * wv.z + rv.w * wv.w;
        }
    }
    if (which == 0) {
        float bias = attn_b[o];
        #pragma unroll
        for (int r = 0; r < 4; r++)
            eq[(row0 + r) * Hn + o] = fast_exp2(C2 * (acc[r] + bias));
    } else {
        float4 ev;
        ev.x = fast_exp2(C2 * acc[0]); ev.y = fast_exp2(C2 * acc[1]);
        ev.z = fast_exp2(C2 * acc[2]); ev.w = fast_exp2(C2 * acc[3]);
        *reinterpret_cast<float4*>(&ekT[(size_t)(b * Hn + o) * Sn + t0]) = ev;
    }
}

// Kernel 2: raw logits -> out_w. LDS-free, sync-free, wave-uniform q.
// grid (Sn/ST=128, Bn, 2 t-halves) = 1024 blocks x 256 threads (4 waves).
// wave = one s-row; lane = 4 consecutive t (dwordx4 ek loads, contiguous 1KB/wave).
__global__ __launch_bounds__(256) void score_kernel(
    const float* __restrict__ eq, const float* __restrict__ ekT,
    const float* __restrict__ v_w, float* __restrict__ logits)
{
    const int b  = blockIdx.y;
    const int s  = blockIdx.x * ST + (threadIdx.x >> 6);   // wave-uniform
    const int t0 = blockIdx.z * 256 + (threadIdx.x & 63) * 4;

    const float* kb   = ekT + (size_t)b * Hn * Sn + t0;
    const float* qrow = eq + (size_t)(b * Sn + s) * Hn;    // wave-uniform address

    float a0 = 0.f, a1 = 0.f, a2 = 0.f, a3 = 0.f;
    for (int h = 0; h < Hn; h += 8) {
        // wave-uniform broadcast loads (L1-resident after first touch)
        float4 qA = *reinterpret_cast<const float4*>(qrow + h);
        float4 qB = *reinterpret_cast<const float4*>(qrow + h + 4);
        float4 wA = *reinterpret_cast<const float4*>(v_w + h);
        float4 wB = *reinterpret_cast<const float4*>(v_w + h + 4);
        const float qj[8] = {qA.x, qA.y, qA.z, qA.w, qB.x, qB.y, qB.z, qB.w};
        const float wj[8] = {wA.x, wA.y, wA.z, wA.w, wB.x, wB.y, wB.z, wB.w};
        #pragma unroll
        for (int j = 0; j < 8; j++) {
            float4 e = *reinterpret_cast<const float4*>(kb + (size_t)(h + j) * Sn);
            const float q = qj[j], w = wj[j];
            a0 += w * fast_rcp(q * e.x + 1.0f);
            a1 += w * fast_rcp(q * e.y + 1.0f);
            a2 += w * fast_rcp(q * e.z + 1.0f);
            a3 += w * fast_rcp(q * e.w + 1.0f);
        }
    }
    float4 o;
    o.x = -2.0f * a0; o.y = -2.0f * a1; o.z = -2.0f * a2; o.w = -2.0f * a3;
    *reinterpret_cast<float4*>(logits + (size_t)(b * Sn + s) * Sn + t0) = o;
}

// Kernel 3: softmax (in-place on out_w) + PV.  512 threads, grid (Sn/ST, Bn).
__global__ __launch_bounds__(512) void softpv_kernel(
    const float* __restrict__ value, float* __restrict__ out,
    float* __restrict__ out_w)
{
    __shared__ float4 scT4[Sn];               // weights transposed  8 KB
    __shared__ float4 part4[16][ST][Hn / 4];  // PV partials        32 KB

    const int b   = blockIdx.y;
    const int s0  = blockIdx.x * ST;
    const int tid = threadIdx.x;
    const int wave = tid >> 6, lane = tid & 63;

    if (wave < ST) {
        const int sr = wave;
        float* row = out_w + (size_t)(b * Sn + s0 + sr) * Sn;
        float v[8]; float m = -1e30f;
        #pragma unroll
        for (int i = 0; i < 8; i++) { v[i] = row[lane + i * 64]; m = fmaxf(m, v[i]); }
        #pragma unroll
        for (int off = 32; off; off >>= 1) m = fmaxf(m, __shfl_xor(m, off, 64));
        float sum = 0.f;
        const float l2e = 1.4426950408889634f;
        #pragma unroll
        for (int i = 0; i < 8; i++) { v[i] = fast_exp2((v[i] - m) * l2e); sum += v[i]; }
        #pragma unroll
        for (int off = 32; off; off >>= 1) sum += __shfl_xor(sum, off, 64);
        float inv = 1.0f / sum;
        #pragma unroll
        for (int i = 0; i < 8; i++) {
            float wgt = v[i] * inv;
            row[lane + i * 64] = wgt;                  // normalized weights out
            ((float*)&scT4[lane + i * 64])[sr] = wgt;  // transposed copy for PV
        }
    }
    __syncthreads();

    // PV: thread = (tg in 16, hq in 32); value read once per block
    {
        const int hq = tid & 31, tg = tid >> 5;
        const float* vb = value + ((size_t)b * Sn + tg * 32) * Hn + hq * 4;
        float4 A0 = {0,0,0,0}, A1 = {0,0,0,0}, A2 = {0,0,0,0}, A3 = {0,0,0,0};
        #pragma unroll 4
        for (int i = 0; i < 32; i++) {
            float4 v4 = *reinterpret_cast<const float4*>(vb + i * Hn);
            float4 w4 = scT4[tg * 32 + i];     // b128 broadcast
            A0.x += w4.x * v4.x; A0.y += w4.x * v4.y; A0.z += w4.x * v4.z; A0.w += w4.x * v4.w;
            A1.x += w4.y * v4.x; A1.y += w4.y * v4.y; A1.z += w4.y * v4.z; A1.w += w4.y * v4.w;
            A2.x += w4.z * v4.x; A2.y += w4.z * v4.y; A2.z += w4.z * v4.z; A2.w += w4.z * v4.w;
            A3.x += w4.w * v4.x; A3.y += w4.w * v4.y; A3.z += w4.w * v4.z; A3.w += w4.w * v4.w;
        }
        part4[tg][0][hq] = A0;
        part4[tg][1][hq] = A1;
        part4[tg][2][hq] = A2;
        part4[tg][3][hq] = A3;
    }
    __syncthreads();
    {
        const int sg = tid >> 7, h = tid & 127;
        float r = 0.f;
        #pragma unroll
        for (int tg = 0; tg < 16; tg++)
            r += ((const float*)&part4[tg][sg][h >> 2])[h & 3];
        out[(b * Sn + s0 + sg) * Hn + h] = r;
    }
}

extern "C" void kernel_launch(void* const* d_in, const int* in_sizes, int n_in,
                              void* d_out, int out_size, void* d_ws, size_t ws_size,
                              hipStream_t stream) {
    const float* query  = (const float*)d_in[0];
    const float* key    = (const float*)d_in[1];
    const float* value  = (const float*)d_in[2];
    const float* attn_W = (const float*)d_in[3];
    const float* attn_b = (const float*)d_in[4];
    const float* v_w    = (const float*)d_in[5];

    float* out   = (float*)d_out;            // (B,S,H) then (B,S,S), both f32
    float* out_w = out + Bn * Sn * Hn;

    float* eq  = (float*)d_ws;               // B*S*H floats = 1 MB
    float* ekT = eq + Bn * Sn * Hn;          // B*H*S floats = 1 MB

    proj_kernel<<<Bn * Sn / 4, 256, 0, stream>>>(query, key, attn_W, attn_b, eq, ekT);
    score_kernel<<<dim3(Sn / ST, Bn, 2), 256, 0, stream>>>(eq, ekT, v_w, out_w);
    softpv_kernel<<<dim3(Sn / ST, Bn), 512, 0, stream>>>(value, out, out_w);
}